// Round 1
// baseline (60.814 us; speedup 1.0000x reference)
//
#include <hip/hip_runtime.h>

// EmbeddingBagCollection:
//   p0 = sum-pool(E0[idx0], len0)  -> [B, 64]
//   p1 = sum-pool(E1[idx1], len1)  -> [B, 128]
//   out = concat([p0, p1], dim=1)  -> [B, 192]
//
// B=16384, L=50 (padded), E0: [1e6, 64] f32, E1: [1e5, 128] f32.
// Gather-bound. One wave per (bag, table); float4 gathers; shfl_xor reduce.

#define BB 16384
#define LL 50
#define D0 64
#define D1 128
#define DOUT 192

__global__ __launch_bounds__(256) void embbag_kernel(
    const int* __restrict__ idx0, const int* __restrict__ len0,
    const int* __restrict__ idx1, const int* __restrict__ len1,
    const float* __restrict__ E0, const float* __restrict__ E1,
    float* __restrict__ out)
{
    const int t    = threadIdx.x;
    const int wid  = t >> 6;        // 0..3
    const int lane = t & 63;
    // 2 bags per block: waves {0,1} -> bag0 (tables 0,1), waves {2,3} -> bag1
    const int b = blockIdx.x * 2 + (wid >> 1);
    const int table = wid & 1;
    if (b >= BB) return;

    if (table == 0) {
        // ---- table 0: D0=64 floats = 16 float4; 4 rows in flight per wave ----
        const int sub = lane >> 4;   // 0..3 : which row of the chunk
        const int j   = lane & 15;   // float4 index within row
        const int n   = len0[b];
        const int* __restrict__ ip = idx0 + b * LL;
        float4 acc = make_float4(0.f, 0.f, 0.f, 0.f);
        for (int base = 0; base < n; base += 4) {
            const int row = base + sub;
            if (row < n) {
                const int id = ip[row];
                const float4 v = *reinterpret_cast<const float4*>(
                    E0 + (size_t)id * D0 + j * 4);
                acc.x += v.x; acc.y += v.y; acc.z += v.z; acc.w += v.w;
            }
        }
        // reduce across the 4 sub-groups (lane strides 16, 32)
        #pragma unroll
        for (int m = 16; m < 64; m <<= 1) {
            acc.x += __shfl_xor(acc.x, m, 64);
            acc.y += __shfl_xor(acc.y, m, 64);
            acc.z += __shfl_xor(acc.z, m, 64);
            acc.w += __shfl_xor(acc.w, m, 64);
        }
        if (sub == 0) {
            *reinterpret_cast<float4*>(out + (size_t)b * DOUT + j * 4) = acc;
        }
    } else {
        // ---- table 1: D1=128 floats = 32 float4; 2 rows in flight per wave ----
        const int sub = lane >> 5;   // 0..1
        const int j   = lane & 31;   // float4 index within row
        const int n   = len1[b];
        const int* __restrict__ ip = idx1 + b * LL;
        float4 acc = make_float4(0.f, 0.f, 0.f, 0.f);
        for (int base = 0; base < n; base += 2) {
            const int row = base + sub;
            if (row < n) {
                const int id = ip[row];
                const float4 v = *reinterpret_cast<const float4*>(
                    E1 + (size_t)id * D1 + j * 4);
                acc.x += v.x; acc.y += v.y; acc.z += v.z; acc.w += v.w;
            }
        }
        acc.x += __shfl_xor(acc.x, 32, 64);
        acc.y += __shfl_xor(acc.y, 32, 64);
        acc.z += __shfl_xor(acc.z, 32, 64);
        acc.w += __shfl_xor(acc.w, 32, 64);
        if (sub == 0) {
            *reinterpret_cast<float4*>(out + (size_t)b * DOUT + D0 + j * 4) = acc;
        }
    }
}

extern "C" void kernel_launch(void* const* d_in, const int* in_sizes, int n_in,
                              void* d_out, int out_size, void* d_ws, size_t ws_size,
                              hipStream_t stream) {
    const int*   idx0 = (const int*)d_in[0];
    const int*   len0 = (const int*)d_in[1];
    const int*   idx1 = (const int*)d_in[2];
    const int*   len1 = (const int*)d_in[3];
    const float* E0   = (const float*)d_in[4];
    const float* E1   = (const float*)d_in[5];
    float* out = (float*)d_out;

    // 2 bags per 256-thread block
    const int grid = BB / 2;
    embbag_kernel<<<grid, 256, 0, stream>>>(idx0, len0, idx1, len1, E0, E1, out);
}

// Round 2
// 52.365 us; speedup vs baseline: 1.1613x; 1.1613x over previous
//
#include <hip/hip_runtime.h>

// EmbeddingBagCollection:
//   p0 = sum-pool(E0[idx0], len0)  -> [B, 64]
//   p1 = sum-pool(E1[idx1], len1)  -> [B, 128]
//   out = concat([p0, p1], dim=1)  -> [B, 192]
//
// Gather-latency-bound. One wave per (bag, table). Indices preloaded once
// per bag (coalesced) and broadcast via shfl; main loop unrolled with
// independent accumulators for 2-4 outstanding float4 gathers per lane.

#define BB 16384
#define LL 50
#define D0 64
#define D1 128
#define DOUT 192

__global__ __launch_bounds__(256) void embbag_kernel(
    const int* __restrict__ idx0, const int* __restrict__ len0,
    const int* __restrict__ idx1, const int* __restrict__ len1,
    const float* __restrict__ E0, const float* __restrict__ E1,
    float* __restrict__ out)
{
    const int t    = threadIdx.x;
    const int wid  = t >> 6;        // 0..3
    const int lane = t & 63;
    // 2 bags per block: waves {0,1} -> bag b0 (tables 0,1), waves {2,3} -> b0+1
    const int b = blockIdx.x * 2 + (wid >> 1);
    const int table = wid & 1;

    if (table == 0) {
        // ---- table 0: row = 16 float4; 4 rows per step, unroll 2 => 8 rows/iter
        const int n   = len0[b];
        const int* __restrict__ ip = idx0 + b * LL;
        const int allidx = ip[lane < LL ? lane : LL - 1];  // coalesced, one load
        const int sub = lane >> 4;   // 0..3
        const int j   = lane & 15;
        float4 a0 = make_float4(0.f,0.f,0.f,0.f);
        float4 a1 = make_float4(0.f,0.f,0.f,0.f);
        const int full = n & ~7;
        for (int base = 0; base < full; base += 8) {
            const int id0 = __shfl(allidx, base + sub,     64);
            const int id1 = __shfl(allidx, base + 4 + sub, 64);
            const float4 v0 = *reinterpret_cast<const float4*>(E0 + (size_t)id0 * D0 + j * 4);
            const float4 v1 = *reinterpret_cast<const float4*>(E0 + (size_t)id1 * D0 + j * 4);
            a0.x += v0.x; a0.y += v0.y; a0.z += v0.z; a0.w += v0.w;
            a1.x += v1.x; a1.y += v1.y; a1.z += v1.z; a1.w += v1.w;
        }
        for (int base = full; base < n; base += 4) {
            const int row = base + sub;
            const int id  = __shfl(allidx, row < n ? row : 0, 64);
            if (row < n) {
                const float4 v = *reinterpret_cast<const float4*>(E0 + (size_t)id * D0 + j * 4);
                a0.x += v.x; a0.y += v.y; a0.z += v.z; a0.w += v.w;
            }
        }
        a0.x += a1.x; a0.y += a1.y; a0.z += a1.z; a0.w += a1.w;
        #pragma unroll
        for (int m = 16; m < 64; m <<= 1) {
            a0.x += __shfl_xor(a0.x, m, 64);
            a0.y += __shfl_xor(a0.y, m, 64);
            a0.z += __shfl_xor(a0.z, m, 64);
            a0.w += __shfl_xor(a0.w, m, 64);
        }
        if (sub == 0) {
            *reinterpret_cast<float4*>(out + (size_t)b * DOUT + j * 4) = a0;
        }
    } else {
        // ---- table 1: row = 32 float4; 2 rows per step, unroll 4 => 8 rows/iter
        const int n   = len1[b];
        const int* __restrict__ ip = idx1 + b * LL;
        const int allidx = ip[lane < LL ? lane : LL - 1];
        const int sub = lane >> 5;   // 0..1
        const int j   = lane & 31;
        float4 a0 = make_float4(0.f,0.f,0.f,0.f);
        float4 a1 = make_float4(0.f,0.f,0.f,0.f);
        float4 a2 = make_float4(0.f,0.f,0.f,0.f);
        float4 a3 = make_float4(0.f,0.f,0.f,0.f);
        const int full = n & ~7;
        for (int base = 0; base < full; base += 8) {
            const int id0 = __shfl(allidx, base + sub,     64);
            const int id1 = __shfl(allidx, base + 2 + sub, 64);
            const int id2 = __shfl(allidx, base + 4 + sub, 64);
            const int id3 = __shfl(allidx, base + 6 + sub, 64);
            const float4 v0 = *reinterpret_cast<const float4*>(E1 + (size_t)id0 * D1 + j * 4);
            const float4 v1 = *reinterpret_cast<const float4*>(E1 + (size_t)id1 * D1 + j * 4);
            const float4 v2 = *reinterpret_cast<const float4*>(E1 + (size_t)id2 * D1 + j * 4);
            const float4 v3 = *reinterpret_cast<const float4*>(E1 + (size_t)id3 * D1 + j * 4);
            a0.x += v0.x; a0.y += v0.y; a0.z += v0.z; a0.w += v0.w;
            a1.x += v1.x; a1.y += v1.y; a1.z += v1.z; a1.w += v1.w;
            a2.x += v2.x; a2.y += v2.y; a2.z += v2.z; a2.w += v2.w;
            a3.x += v3.x; a3.y += v3.y; a3.z += v3.z; a3.w += v3.w;
        }
        for (int base = full; base < n; base += 2) {
            const int row = base + sub;
            const int id  = __shfl(allidx, row < n ? row : 0, 64);
            if (row < n) {
                const float4 v = *reinterpret_cast<const float4*>(E1 + (size_t)id * D1 + j * 4);
                a0.x += v.x; a0.y += v.y; a0.z += v.z; a0.w += v.w;
            }
        }
        a0.x += a1.x + a2.x + a3.x;
        a0.y += a1.y + a2.y + a3.y;
        a0.z += a1.z + a2.z + a3.z;
        a0.w += a1.w + a2.w + a3.w;
        a0.x += __shfl_xor(a0.x, 32, 64);
        a0.y += __shfl_xor(a0.y, 32, 64);
        a0.z += __shfl_xor(a0.z, 32, 64);
        a0.w += __shfl_xor(a0.w, 32, 64);
        if (sub == 0) {
            *reinterpret_cast<float4*>(out + (size_t)b * DOUT + D0 + j * 4) = a0;
        }
    }
}

extern "C" void kernel_launch(void* const* d_in, const int* in_sizes, int n_in,
                              void* d_out, int out_size, void* d_ws, size_t ws_size,
                              hipStream_t stream) {
    const int*   idx0 = (const int*)d_in[0];
    const int*   len0 = (const int*)d_in[1];
    const int*   idx1 = (const int*)d_in[2];
    const int*   len1 = (const int*)d_in[3];
    const float* E0   = (const float*)d_in[4];
    const float* E1   = (const float*)d_in[5];
    float* out = (float*)d_out;

    const int grid = BB / 2;   // 2 bags per 256-thread block
    embbag_kernel<<<grid, 256, 0, stream>>>(idx0, len0, idx1, len1, E0, E1, out);
}

// Round 3
// 51.459 us; speedup vs baseline: 1.1818x; 1.0176x over previous
//
#include <hip/hip_runtime.h>

// EmbeddingBagCollection:
//   p0 = sum-pool(E0[idx0], len0)  -> [B, 64]
//   p1 = sum-pool(E1[idx1], len1)  -> [B, 128]
//   out = concat([p0, p1], dim=1)  -> [B, 192]
//
// Gather-latency-bound. One wave per (bag, table). Static fully-unrolled
// masked gather: all rows issued under one deep vmcnt window (13 loads/lane
// for table0, 25 for table1). Masked rows clamp to row n-1 (cache-hit dup)
// and are zeroed via fmaf scale, so trip count is compile-time.

#define BB 16384
#define LL 50
#define D0 64
#define D1 128
#define DOUT 192

__global__ __launch_bounds__(256, 4) void embbag_kernel(
    const int* __restrict__ idx0, const int* __restrict__ len0,
    const int* __restrict__ idx1, const int* __restrict__ len1,
    const float* __restrict__ E0, const float* __restrict__ E1,
    float* __restrict__ out)
{
    const int t    = threadIdx.x;
    const int wid  = t >> 6;        // 0..3
    const int lane = t & 63;
    // 2 bags per block: waves {0,1} -> bag b0 (tables 0,1), waves {2,3} -> b0+1
    const int b = blockIdx.x * 2 + (wid >> 1);
    const int table = wid & 1;

    if (table == 0) {
        // ---- table 0: row = 16 float4; 4 row-slots (sub), 13 static chunks ----
        const int n   = len0[b];
        const int sub = lane >> 4;   // 0..3
        const int j   = lane & 15;
        float* op = out + (size_t)b * DOUT + j * 4;
        if (n == 0) {
            if (sub == 0) *reinterpret_cast<float4*>(op) = make_float4(0.f,0.f,0.f,0.f);
            return;
        }
        const int* __restrict__ ip = idx0 + b * LL;
        const int allidx = ip[lane < LL ? lane : LL - 1];  // one coalesced load
        float4 a0 = make_float4(0.f,0.f,0.f,0.f);
        float4 a1 = make_float4(0.f,0.f,0.f,0.f);
        #pragma unroll
        for (int c = 0; c < 13; ++c) {
            const int row  = c * 4 + sub;
            const int rowc = row < n ? row : n - 1;          // clamped: dup -> cache hit
            const int id   = __shfl(allidx, rowc, 64);
            const float s  = row < n ? 1.f : 0.f;
            const float4 v = *reinterpret_cast<const float4*>(
                E0 + (size_t)id * D0 + j * 4);
            if (c & 1) {
                a1.x = fmaf(v.x, s, a1.x); a1.y = fmaf(v.y, s, a1.y);
                a1.z = fmaf(v.z, s, a1.z); a1.w = fmaf(v.w, s, a1.w);
            } else {
                a0.x = fmaf(v.x, s, a0.x); a0.y = fmaf(v.y, s, a0.y);
                a0.z = fmaf(v.z, s, a0.z); a0.w = fmaf(v.w, s, a0.w);
            }
        }
        a0.x += a1.x; a0.y += a1.y; a0.z += a1.z; a0.w += a1.w;
        #pragma unroll
        for (int m = 16; m < 64; m <<= 1) {
            a0.x += __shfl_xor(a0.x, m, 64);
            a0.y += __shfl_xor(a0.y, m, 64);
            a0.z += __shfl_xor(a0.z, m, 64);
            a0.w += __shfl_xor(a0.w, m, 64);
        }
        if (sub == 0) {
            *reinterpret_cast<float4*>(op) = a0;
        }
    } else {
        // ---- table 1: row = 32 float4; 2 row-slots (sub), 25 static chunks ----
        const int n   = len1[b];
        const int sub = lane >> 5;   // 0..1
        const int j   = lane & 31;
        float* op = out + (size_t)b * DOUT + D0 + j * 4;
        if (n == 0) {
            if (sub == 0) *reinterpret_cast<float4*>(op) = make_float4(0.f,0.f,0.f,0.f);
            return;
        }
        const int* __restrict__ ip = idx1 + b * LL;
        const int allidx = ip[lane < LL ? lane : LL - 1];
        float4 a0 = make_float4(0.f,0.f,0.f,0.f);
        float4 a1 = make_float4(0.f,0.f,0.f,0.f);
        #pragma unroll
        for (int c = 0; c < 25; ++c) {
            const int row  = c * 2 + sub;
            const int rowc = row < n ? row : n - 1;
            const int id   = __shfl(allidx, rowc, 64);
            const float s  = row < n ? 1.f : 0.f;
            const float4 v = *reinterpret_cast<const float4*>(
                E1 + (size_t)id * D1 + j * 4);
            if (c & 1) {
                a1.x = fmaf(v.x, s, a1.x); a1.y = fmaf(v.y, s, a1.y);
                a1.z = fmaf(v.z, s, a1.z); a1.w = fmaf(v.w, s, a1.w);
            } else {
                a0.x = fmaf(v.x, s, a0.x); a0.y = fmaf(v.y, s, a0.y);
                a0.z = fmaf(v.z, s, a0.z); a0.w = fmaf(v.w, s, a0.w);
            }
        }
        a0.x += a1.x; a0.y += a1.y; a0.z += a1.z; a0.w += a1.w;
        a0.x += __shfl_xor(a0.x, 32, 64);
        a0.y += __shfl_xor(a0.y, 32, 64);
        a0.z += __shfl_xor(a0.z, 32, 64);
        a0.w += __shfl_xor(a0.w, 32, 64);
        if (sub == 0) {
            *reinterpret_cast<float4*>(op) = a0;
        }
    }
}

extern "C" void kernel_launch(void* const* d_in, const int* in_sizes, int n_in,
                              void* d_out, int out_size, void* d_ws, size_t ws_size,
                              hipStream_t stream) {
    const int*   idx0 = (const int*)d_in[0];
    const int*   len0 = (const int*)d_in[1];
    const int*   idx1 = (const int*)d_in[2];
    const int*   len1 = (const int*)d_in[3];
    const float* E0   = (const float*)d_in[4];
    const float* E1   = (const float*)d_in[5];
    float* out = (float*)d_out;

    const int grid = BB / 2;   // 2 bags per 256-thread block
    embbag_kernel<<<grid, 256, 0, stream>>>(idx0, len0, idx1, len1, E0, E1, out);
}

// Round 5
// 51.053 us; speedup vs baseline: 1.1912x; 1.0080x over previous
//
#include <hip/hip_runtime.h>

// EmbeddingBagCollection:
//   p0 = sum-pool(E0[idx0], len0)  -> [B, 64]
//   p1 = sum-pool(E1[idx1], len1)  -> [B, 128]
//   out = concat([p0, p1], dim=1)  -> [B, 192]
//
// Round 5 = round 3 structure, E0 gathers non-temporal (streamed, low cache
// priority) so the high-reuse E1 (51 MB, ~4.1 touches/row) stays L2/L3
// resident. Uses a native ext_vector_type for the nontemporal builtin
// (HIP_vector_type<float,4>* is rejected by clang).

#define BB 16384
#define LL 50
#define D0 64
#define D1 128
#define DOUT 192

typedef float f32x4 __attribute__((ext_vector_type(4)));

__global__ __launch_bounds__(256, 4) void embbag_kernel(
    const int* __restrict__ idx0, const int* __restrict__ len0,
    const int* __restrict__ idx1, const int* __restrict__ len1,
    const float* __restrict__ E0, const float* __restrict__ E1,
    float* __restrict__ out)
{
    const int t    = threadIdx.x;
    const int wid  = t >> 6;        // 0..3
    const int lane = t & 63;
    // 2 bags per block: waves {0,1} -> bag b0 (tables 0,1), waves {2,3} -> b0+1
    const int b = blockIdx.x * 2 + (wid >> 1);
    const int table = wid & 1;

    if (table == 0) {
        // ---- table 0: row = 16 float4; 4 row-slots (sub), 13 static chunks ----
        const int n   = len0[b];
        const int sub = lane >> 4;   // 0..3
        const int j   = lane & 15;
        float* op = out + (size_t)b * DOUT + j * 4;
        if (n == 0) {
            if (sub == 0) *reinterpret_cast<f32x4*>(op) = (f32x4)(0.f);
            return;
        }
        const int* __restrict__ ip = idx0 + b * LL;
        const int allidx = ip[lane < LL ? lane : LL - 1];  // one coalesced load
        f32x4 a0 = (f32x4)(0.f);
        f32x4 a1 = (f32x4)(0.f);
        #pragma unroll
        for (int c = 0; c < 13; ++c) {
            const int row  = c * 4 + sub;
            const int rowc = row < n ? row : n - 1;          // clamped: dup -> cache hit
            const int id   = __shfl(allidx, rowc, 64);
            const float s  = row < n ? 1.f : 0.f;
            // Non-temporal: stream E0, don't evict E1 from L2/L3.
            const f32x4 v = __builtin_nontemporal_load(
                reinterpret_cast<const f32x4*>(E0 + (size_t)id * D0 + j * 4));
            if (c & 1) a1 += v * s; else a0 += v * s;
        }
        a0 += a1;
        #pragma unroll
        for (int m = 16; m < 64; m <<= 1) {
            a0.x += __shfl_xor(a0.x, m, 64);
            a0.y += __shfl_xor(a0.y, m, 64);
            a0.z += __shfl_xor(a0.z, m, 64);
            a0.w += __shfl_xor(a0.w, m, 64);
        }
        if (sub == 0) {
            *reinterpret_cast<f32x4*>(op) = a0;
        }
    } else {
        // ---- table 1: row = 32 float4; 2 row-slots (sub), 25 static chunks ----
        const int n   = len1[b];
        const int sub = lane >> 5;   // 0..1
        const int j   = lane & 31;
        float* op = out + (size_t)b * DOUT + D0 + j * 4;
        if (n == 0) {
            if (sub == 0) *reinterpret_cast<f32x4*>(op) = (f32x4)(0.f);
            return;
        }
        const int* __restrict__ ip = idx1 + b * LL;
        const int allidx = ip[lane < LL ? lane : LL - 1];
        f32x4 a0 = (f32x4)(0.f);
        f32x4 a1 = (f32x4)(0.f);
        #pragma unroll
        for (int c = 0; c < 25; ++c) {
            const int row  = c * 2 + sub;
            const int rowc = row < n ? row : n - 1;
            const int id   = __shfl(allidx, rowc, 64);
            const float s  = row < n ? 1.f : 0.f;
            // E1: normal (temporal) loads — high reuse, keep cached.
            const f32x4 v = *reinterpret_cast<const f32x4*>(
                E1 + (size_t)id * D1 + j * 4);
            if (c & 1) a1 += v * s; else a0 += v * s;
        }
        a0 += a1;
        a0.x += __shfl_xor(a0.x, 32, 64);
        a0.y += __shfl_xor(a0.y, 32, 64);
        a0.z += __shfl_xor(a0.z, 32, 64);
        a0.w += __shfl_xor(a0.w, 32, 64);
        if (sub == 0) {
            *reinterpret_cast<f32x4*>(op) = a0;
        }
    }
}

extern "C" void kernel_launch(void* const* d_in, const int* in_sizes, int n_in,
                              void* d_out, int out_size, void* d_ws, size_t ws_size,
                              hipStream_t stream) {
    const int*   idx0 = (const int*)d_in[0];
    const int*   len0 = (const int*)d_in[1];
    const int*   idx1 = (const int*)d_in[2];
    const int*   len1 = (const int*)d_in[3];
    const float* E0   = (const float*)d_in[4];
    const float* E1   = (const float*)d_in[5];
    float* out = (float*)d_out;

    const int grid = BB / 2;   // 2 bags per 256-thread block
    embbag_kernel<<<grid, 256, 0, stream>>>(idx0, len0, idx1, len1, E0, E1, out);
}